// Round 10
// baseline (177.931 us; speedup 1.0000x reference)
//
#include <hip/hip_runtime.h>

#define NEDGE  1600000
#define NPT    (NEDGE / 16)   // 100000 16-edge tiles
#define GRID   2500           // one wave-pair per block
#define NIT    (NPT / GRID)   // 40 — exact
#define ESTEP  (GRID * 16)    // edge-row stride per iteration
#define NNODE  100000
#define NB_OFF 32768                       // ushort offset of bf16 node cache in ws
#define WS_BYTES (65536 + NNODE * 32 * 2)  // frags + bf16 nodes = 6,465,536

typedef float f32x4  __attribute__((ext_vector_type(4)));
typedef short short8 __attribute__((ext_vector_type(8)));

static __device__ __forceinline__ ushort f2bf(float f) {
  uint u = __builtin_bit_cast(uint, f);
  return (ushort)((u + 0x7FFFu + ((u >> 16) & 1u)) >> 16);   // RNE
}
static __device__ __forceinline__ uint cvt_pk(float lo, float hi) {
  uint r; asm("v_cvt_pk_bf16_f32 %0, %1, %2" : "=v"(r) : "v"(lo), "v"(hi)); return r;
}
static __device__ __forceinline__ float vexp2(float x) {
  float r; asm("v_exp_f32 %0, %1" : "=v"(r) : "v"(x)); return r;
}
static __device__ __forceinline__ float vrcp(float x) {
  float r; asm("v_rcp_f32 %0, %1" : "=v"(r) : "v"(x)); return r;
}
static __device__ __forceinline__ short8 pack8(float4 a, float4 b) {
  uint4 u;
  u.x = cvt_pk(a.x, a.y); u.y = cvt_pk(a.z, a.w);
  u.z = cvt_pk(b.x, b.y); u.w = cvt_pk(b.z, b.w);
  return __builtin_bit_cast(short8, u);
}

// ---- ROUND-5 prep (validated): W1 (scaled -log2e, b1@k=80, zeros to 96,
// hid-permuted P) + W2 (W2^T A-frags) into MFMA fragment layout. 20480 elems.
__global__ void prep_frags(const float* __restrict__ W1, const float* __restrict__ b1,
                           const float* __restrict__ W2, ushort* __restrict__ ws) {
  const int idx = blockIdx.x * 256 + threadIdx.x;
  if (idx >= 20480) return;
  const int frag = idx >> 9;
  const int lane = (idx >> 3) & 63;
  const int j    = idx & 7;
  const int g = lane >> 4, c = lane & 15;
  ushort v;
  if (frag < 30) {                    // W1^T A-frags: frag = wh*15 + mt*3 + kt
    const int wh = frag / 15, rem = frag % 15, mt = rem / 3, kt = rem % 3;
    const int k   = kt * 32 + g * 8 + j;
    const int hid = 32 * mt + 8 * (c >> 2) + 4 * wh + (c & 3);   // permutation P
    const float s = -1.44269504088896f;
    const float val = (k < 80) ? W1[k * 160 + hid] * s
                               : (k == 80 ? b1[hid] * s : 0.0f);
    v = f2bf(val);
  } else {                            // W2^T A-frags: frag-30 = wh*5 + kt
    const int f2 = frag - 30, wh = f2 / 5, kt = f2 % 5;
    const int k = kt * 32 + g * 8 + j;
    v = f2bf(W2[k * 32 + 16 * wh + c]);
  }
  ws[idx] = v;
}

// nodes f32 -> bf16 cache (row = 32 bf16 = 64B)
__global__ void prep_nodes(const float* __restrict__ nodes, ushort* __restrict__ nb) {
  const int idx = blockIdx.x * 256 + threadIdx.x;
  if (idx >= NNODE * 4) return;
  const float4 a = ((const float4*)nodes)[idx * 2];
  const float4 b = ((const float4*)nodes)[idx * 2 + 1];
  *(short8*)(nb + (size_t)idx * 8) = pack8(a, b);
}

// Software-pipelined round-5 kernel: L1 of tile i+1 issues between tile i's
// X-write and the barrier, so the barrier skew is covered by MFMA work.
__global__ __launch_bounds__(128) void edge_mlp_fast(
    const float* __restrict__ edges,
    const int* __restrict__ senders, const int* __restrict__ receivers,
    const float* __restrict__ b2, float* __restrict__ out,
    const ushort* __restrict__ ws)
{
  __shared__ uint2 X[2][2][5][64];   // [wave][buf][kt][lane], 10 KB — round-5 exchange

  const int lane = threadIdx.x & 63;
  const int wh   = threadIdx.x >> 6;
  const int g    = lane >> 4;
  const int c    = lane & 15;
  const ushort* nb = ws + NB_OFF;

  short8 w1f[5][3];
#pragma unroll
  for (int mt = 0; mt < 5; ++mt)
#pragma unroll
    for (int kt = 0; kt < 3; ++kt)
      w1f[mt][kt] = *(const short8*)(ws + ((wh * 15 + mt * 3 + kt) * 64 + lane) * 8);
  short8 w2f[5];
#pragma unroll
  for (int kt = 0; kt < 5; ++kt)
    w2f[kt] = *(const short8*)(ws + ((30 + wh * 5 + kt) * 64 + lane) * 8);

  const float4 b2v = *(const float4*)(b2 + wh * 16 + g * 4);
  const f32x4 b2c = (f32x4){b2v.x, b2v.y, b2v.z, b2v.w};
  const f32x4 z4  = (f32x4){0.f, 0.f, 0.f, 0.f};
  const uint  cE0 = (g == 2) ? 0x3F80u : 0u;   // bf16(1.0) ones-column at k==80

  int e = blockIdx.x * 16 + c;       // tile 0 edge row

  // ---- prologue: tile-0 gather, tile-0 L1, tile-1 gather, tile-2 indices ----
  short8 nS, nR;
  float4 ee0, ee1;
  {
    const int si = senders[e], ri = receivers[e];
    nS = *(const short8*)(nb + (size_t)si * 32 + g * 8);
    nR = *(const short8*)(nb + (size_t)ri * 32 + g * 8);
    const float* ep = edges + (size_t)e * 16 + (g & 1) * 8;
    ee0 = *(const float4*)ep;  ee1 = *(const float4*)(ep + 4);
  }
  int si1 = senders[e + ESTEP], ri1 = receivers[e + ESTEP];

  f32x4 acc[5];
  {
    uint4 ue;
    ue.x = (g < 2) ? cvt_pk(ee0.x, ee0.y) : cE0;
    ue.y = (g < 2) ? cvt_pk(ee0.z, ee0.w) : 0u;
    ue.z = (g < 2) ? cvt_pk(ee1.x, ee1.y) : 0u;
    ue.w = (g < 2) ? cvt_pk(ee1.z, ee1.w) : 0u;
    const short8 bfE = __builtin_bit_cast(short8, ue);
#pragma unroll
    for (int mt = 0; mt < 5; ++mt)
      acc[mt] = __builtin_amdgcn_mfma_f32_16x16x32_bf16(w1f[mt][0], nS, z4, 0, 0, 0);
#pragma unroll
    for (int mt = 0; mt < 5; ++mt)
      acc[mt] = __builtin_amdgcn_mfma_f32_16x16x32_bf16(w1f[mt][1], nR, acc[mt], 0, 0, 0);
#pragma unroll
    for (int mt = 0; mt < 5; ++mt)
      acc[mt] = __builtin_amdgcn_mfma_f32_16x16x32_bf16(w1f[mt][2], bfE, acc[mt], 0, 0, 0);
  }
  {  // gather tile 1 into nS/nR/ee; indices for tile 2
    nS = *(const short8*)(nb + (size_t)si1 * 32 + g * 8);
    nR = *(const short8*)(nb + (size_t)ri1 * 32 + g * 8);
    const float* ep = edges + (size_t)(e + ESTEP) * 16 + (g & 1) * 8;
    ee0 = *(const float4*)ep;  ee1 = *(const float4*)(ep + 4);
    si1 = senders[e + 2 * ESTEP];  ri1 = receivers[e + 2 * ESTEP];
  }

  // ---- main loop: tiles 0..38 stored; acc holds tile i, nS/nR/ee tile i+1 ----
#pragma unroll 1
  for (int i = 0; i < NIT - 1; ++i) {
    // 1) sigmoid(acc_i) -> pk (scale pre-folded: h = rcp(1+exp2(x)))
    uint pkA[5], pkB[5];
#pragma unroll
    for (int mt = 0; mt < 5; ++mt) {
      const float h0 = vrcp(1.0f + vexp2(acc[mt][0]));
      const float h1 = vrcp(1.0f + vexp2(acc[mt][1]));
      const float h2 = vrcp(1.0f + vexp2(acc[mt][2]));
      const float h3 = vrcp(1.0f + vexp2(acc[mt][3]));
      pkA[mt] = cvt_pk(h0, h1);
      pkB[mt] = cvt_pk(h2, h3);
    }
    // 2) exchange write (round-5 layout)
#pragma unroll
    for (int kt = 0; kt < 5; ++kt)
      X[wh][i & 1][kt][lane] = make_uint2(pkA[kt], pkB[kt]);

    // 3+4) L1 for tile i+1 (independent work that rides the barrier wait)
    f32x4 accN[5];
    {
      uint4 ue;
      ue.x = (g < 2) ? cvt_pk(ee0.x, ee0.y) : cE0;
      ue.y = (g < 2) ? cvt_pk(ee0.z, ee0.w) : 0u;
      ue.z = (g < 2) ? cvt_pk(ee1.x, ee1.y) : 0u;
      ue.w = (g < 2) ? cvt_pk(ee1.z, ee1.w) : 0u;
      const short8 bfE = __builtin_bit_cast(short8, ue);
#pragma unroll
      for (int mt = 0; mt < 5; ++mt)
        accN[mt] = __builtin_amdgcn_mfma_f32_16x16x32_bf16(w1f[mt][0], nS, z4, 0, 0, 0);
#pragma unroll
      for (int mt = 0; mt < 5; ++mt)
        accN[mt] = __builtin_amdgcn_mfma_f32_16x16x32_bf16(w1f[mt][1], nR, accN[mt], 0, 0, 0);
#pragma unroll
      for (int mt = 0; mt < 5; ++mt)
        accN[mt] = __builtin_amdgcn_mfma_f32_16x16x32_bf16(w1f[mt][2], bfE, accN[mt], 0, 0, 0);
    }

    // 5) prefetch tile i+2 gather + tile i+3 indices (uniform scalar clamps)
    {
      nS = *(const short8*)(nb + (size_t)si1 * 32 + g * 8);
      nR = *(const short8*)(nb + (size_t)ri1 * 32 + g * 8);
      const int off2 = (i + 2 < NIT) ? 2 * ESTEP : 0;
      const float* ep = edges + (size_t)(e + off2) * 16 + (g & 1) * 8;
      ee0 = *(const float4*)ep;  ee1 = *(const float4*)(ep + 4);
      const int off3 = (i + 3 < NIT) ? 3 * ESTEP : 0;
      si1 = senders[e + off3];  ri1 = receivers[e + off3];
    }

    // 6) barrier (LDS drained; vmcnt prefetch stays in flight)
    __builtin_amdgcn_sched_barrier(0);
    asm volatile("s_waitcnt lgkmcnt(0)\n\ts_barrier" ::: "memory");

    // 7) L2 for tile i (round-5/7 dual chain, b2 rides C of chain a) + store
    {
      uint2 q[5];
#pragma unroll
      for (int kt = 0; kt < 5; ++kt) q[kt] = X[wh ^ 1][i & 1][kt][lane];
      f32x4 oa, ob;
      if (wh == 0) {
        oa = __builtin_amdgcn_mfma_f32_16x16x32_bf16(w2f[0],
               __builtin_bit_cast(short8, make_uint4(pkA[0], pkB[0], q[0].x, q[0].y)), b2c, 0, 0, 0);
        ob = __builtin_amdgcn_mfma_f32_16x16x32_bf16(w2f[1],
               __builtin_bit_cast(short8, make_uint4(pkA[1], pkB[1], q[1].x, q[1].y)), z4, 0, 0, 0);
        oa = __builtin_amdgcn_mfma_f32_16x16x32_bf16(w2f[2],
               __builtin_bit_cast(short8, make_uint4(pkA[2], pkB[2], q[2].x, q[2].y)), oa, 0, 0, 0);
        ob = __builtin_amdgcn_mfma_f32_16x16x32_bf16(w2f[3],
               __builtin_bit_cast(short8, make_uint4(pkA[3], pkB[3], q[3].x, q[3].y)), ob, 0, 0, 0);
        oa = __builtin_amdgcn_mfma_f32_16x16x32_bf16(w2f[4],
               __builtin_bit_cast(short8, make_uint4(pkA[4], pkB[4], q[4].x, q[4].y)), oa, 0, 0, 0);
      } else {
        oa = __builtin_amdgcn_mfma_f32_16x16x32_bf16(w2f[0],
               __builtin_bit_cast(short8, make_uint4(q[0].x, q[0].y, pkA[0], pkB[0])), b2c, 0, 0, 0);
        ob = __builtin_amdgcn_mfma_f32_16x16x32_bf16(w2f[1],
               __builtin_bit_cast(short8, make_uint4(q[1].x, q[1].y, pkA[1], pkB[1])), z4, 0, 0, 0);
        oa = __builtin_amdgcn_mfma_f32_16x16x32_bf16(w2f[2],
               __builtin_bit_cast(short8, make_uint4(q[2].x, q[2].y, pkA[2], pkB[2])), oa, 0, 0, 0);
        ob = __builtin_amdgcn_mfma_f32_16x16x32_bf16(w2f[3],
               __builtin_bit_cast(short8, make_uint4(q[3].x, q[3].y, pkA[3], pkB[3])), ob, 0, 0, 0);
        oa = __builtin_amdgcn_mfma_f32_16x16x32_bf16(w2f[4],
               __builtin_bit_cast(short8, make_uint4(q[4].x, q[4].y, pkA[4], pkB[4])), oa, 0, 0, 0);
      }
      const f32x4 o = oa + ob;
      float4 st; st.x = o[0]; st.y = o[1]; st.z = o[2]; st.w = o[3];
      *(float4*)(out + (size_t)e * 32 + wh * 16 + g * 4) = st;
    }

    // 8) advance pipeline state
#pragma unroll
    for (int mt = 0; mt < 5; ++mt) acc[mt] = accN[mt];
    e += ESTEP;
  }

  // ---- epilogue: tile NIT-1 (buf = (NIT-1)&1 = 1; loop last used 0) ----
  {
    uint pkA[5], pkB[5];
#pragma unroll
    for (int mt = 0; mt < 5; ++mt) {
      const float h0 = vrcp(1.0f + vexp2(acc[mt][0]));
      const float h1 = vrcp(1.0f + vexp2(acc[mt][1]));
      const float h2 = vrcp(1.0f + vexp2(acc[mt][2]));
      const float h3 = vrcp(1.0f + vexp2(acc[mt][3]));
      pkA[mt] = cvt_pk(h0, h1);
      pkB[mt] = cvt_pk(h2, h3);
    }
#pragma unroll
    for (int kt = 0; kt < 5; ++kt)
      X[wh][1][kt][lane] = make_uint2(pkA[kt], pkB[kt]);
    asm volatile("s_waitcnt lgkmcnt(0)\n\ts_barrier" ::: "memory");
    uint2 q[5];
#pragma unroll
    for (int kt = 0; kt < 5; ++kt) q[kt] = X[wh ^ 1][1][kt][lane];
    f32x4 oa, ob;
    if (wh == 0) {
      oa = __builtin_amdgcn_mfma_f32_16x16x32_bf16(w2f[0],
             __builtin_bit_cast(short8, make_uint4(pkA[0], pkB[0], q[0].x, q[0].y)), b2c, 0, 0, 0);
      ob = __builtin_amdgcn_mfma_f32_16x16x32_bf16(w2f[1],
             __builtin_bit_cast(short8, make_uint4(pkA[1], pkB[1], q[1].x, q[1].y)), z4, 0, 0, 0);
      oa = __builtin_amdgcn_mfma_f32_16x16x32_bf16(w2f[2],
             __builtin_bit_cast(short8, make_uint4(pkA[2], pkB[2], q[2].x, q[2].y)), oa, 0, 0, 0);
      ob = __builtin_amdgcn_mfma_f32_16x16x32_bf16(w2f[3],
             __builtin_bit_cast(short8, make_uint4(pkA[3], pkB[3], q[3].x, q[3].y)), ob, 0, 0, 0);
      oa = __builtin_amdgcn_mfma_f32_16x16x32_bf16(w2f[4],
             __builtin_bit_cast(short8, make_uint4(pkA[4], pkB[4], q[4].x, q[4].y)), oa, 0, 0, 0);
    } else {
      oa = __builtin_amdgcn_mfma_f32_16x16x32_bf16(w2f[0],
             __builtin_bit_cast(short8, make_uint4(q[0].x, q[0].y, pkA[0], pkB[0])), b2c, 0, 0, 0);
      ob = __builtin_amdgcn_mfma_f32_16x16x32_bf16(w2f[1],
             __builtin_bit_cast(short8, make_uint4(q[1].x, q[1].y, pkA[1], pkB[1])), z4, 0, 0, 0);
      oa = __builtin_amdgcn_mfma_f32_16x16x32_bf16(w2f[2],
             __builtin_bit_cast(short8, make_uint4(q[2].x, q[2].y, pkA[2], pkB[2])), oa, 0, 0, 0);
      ob = __builtin_amdgcn_mfma_f32_16x16x32_bf16(w2f[3],
             __builtin_bit_cast(short8, make_uint4(q[3].x, q[3].y, pkA[3], pkB[3])), ob, 0, 0, 0);
      oa = __builtin_amdgcn_mfma_f32_16x16x32_bf16(w2f[4],
             __builtin_bit_cast(short8, make_uint4(q[4].x, q[4].y, pkA[4], pkB[4])), oa, 0, 0, 0);
    }
    const f32x4 o = oa + ob;
    float4 st; st.x = o[0]; st.y = o[1]; st.z = o[2]; st.w = o[3];
    *(float4*)(out + (size_t)e * 32 + wh * 16 + g * 4) = st;
  }
}

// Fallback (ws too small): round-5 depth-1 path, frags built in-kernel.
__global__ __launch_bounds__(128) void edge_mlp_ref(
    const float* __restrict__ nodes, const float* __restrict__ edges,
    const int* __restrict__ senders, const int* __restrict__ receivers,
    const float* __restrict__ W1, const float* __restrict__ b1,
    const float* __restrict__ W2, const float* __restrict__ b2,
    float* __restrict__ out)
{
  __shared__ uint2 Xr[2][2][5][64];
  const int lane = threadIdx.x & 63;
  const int wh   = threadIdx.x >> 6;
  const int g    = lane >> 4;
  const int c    = lane & 15;

  short8 w1f[5][3];
  short8 w2f[5];
  const float s = -1.44269504088896f;
  const int hidb = 8 * (c >> 2) + 4 * wh + (c & 3);
#pragma unroll
  for (int mt = 0; mt < 5; ++mt)
#pragma unroll
    for (int kt = 0; kt < 3; ++kt) {
      const int hid = 32 * mt + hidb;
      uint d[4];
#pragma unroll
      for (int dw = 0; dw < 4; ++dw) {
        const int k0 = kt * 32 + g * 8 + dw * 2, k1 = k0 + 1;
        const float f0 = (k0 < 80) ? W1[k0 * 160 + hid] * s : (k0 == 80 ? b1[hid] * s : 0.f);
        const float f1 = (k1 < 80) ? W1[k1 * 160 + hid] * s : (k1 == 80 ? b1[hid] * s : 0.f);
        d[dw] = (uint)f2bf(f0) | ((uint)f2bf(f1) << 16);
      }
      w1f[mt][kt] = __builtin_bit_cast(short8, make_uint4(d[0], d[1], d[2], d[3]));
    }
#pragma unroll
  for (int kt = 0; kt < 5; ++kt) {
    uint d[4];
#pragma unroll
    for (int dw = 0; dw < 4; ++dw) {
      const int k = kt * 32 + g * 8 + dw * 2;
      d[dw] = (uint)f2bf(W2[k * 32 + wh * 16 + c]) |
              ((uint)f2bf(W2[(k + 1) * 32 + wh * 16 + c]) << 16);
    }
    w2f[kt] = __builtin_bit_cast(short8, make_uint4(d[0], d[1], d[2], d[3]));
  }
  const float4 b2v = *(const float4*)(b2 + wh * 16 + g * 4);
  const f32x4 b2c = (f32x4){b2v.x, b2v.y, b2v.z, b2v.w};
  const f32x4 z4  = (f32x4){0.f, 0.f, 0.f, 0.f};
  const uint  cE0 = (g == 2) ? 0x3F80u : 0u;

  int t = blockIdx.x;
  int e = t * 16 + c;
  float4 sn0, sn1, rn0, rn1, ee0, ee1;
  {
    const int si = senders[e], ri = receivers[e];
    const float* sp = nodes + (size_t)si * 32 + g * 8;
    sn0 = *(const float4*)sp;  sn1 = *(const float4*)(sp + 4);
    const float* rp = nodes + (size_t)ri * 32 + g * 8;
    rn0 = *(const float4*)rp;  rn1 = *(const float4*)(rp + 4);
    const float* ep = edges + (size_t)e * 16 + (g & 1) * 8;
    ee0 = *(const float4*)ep;  ee1 = *(const float4*)(ep + 4);
  }
  int e1 = (t + GRID) * 16 + c;
  int si1 = senders[e1], ri1 = receivers[e1];

  for (int i = 0; i < NIT; ++i) {
    const int buf = i & 1;
    uint4 ue;
    ue.x = (g < 2) ? cvt_pk(ee0.x, ee0.y) : cE0;
    ue.y = (g < 2) ? cvt_pk(ee0.z, ee0.w) : 0u;
    ue.z = (g < 2) ? cvt_pk(ee1.x, ee1.y) : 0u;
    ue.w = (g < 2) ? cvt_pk(ee1.z, ee1.w) : 0u;
    const short8 bfE = __builtin_bit_cast(short8, ue);
    const short8 bfS = pack8(sn0, sn1);
    const short8 bfR = pack8(rn0, rn1);

    f32x4 acc[5];
#pragma unroll
    for (int mt = 0; mt < 5; ++mt)
      acc[mt] = __builtin_amdgcn_mfma_f32_16x16x32_bf16(w1f[mt][0], bfS, z4, 0, 0, 0);
#pragma unroll
    for (int mt = 0; mt < 5; ++mt)
      acc[mt] = __builtin_amdgcn_mfma_f32_16x16x32_bf16(w1f[mt][1], bfR, acc[mt], 0, 0, 0);
#pragma unroll
    for (int mt = 0; mt < 5; ++mt)
      acc[mt] = __builtin_amdgcn_mfma_f32_16x16x32_bf16(w1f[mt][2], bfE, acc[mt], 0, 0, 0);

    {
      int tn = t + GRID; if (tn >= NPT) tn = t;
      const int en = tn * 16 + c;
      const float* epn = edges + (size_t)en * 16 + (g & 1) * 8;
      ee0 = *(const float4*)epn;  ee1 = *(const float4*)(epn + 4);
      const float* spn = nodes + (size_t)si1 * 32 + g * 8;
      sn0 = *(const float4*)spn;  sn1 = *(const float4*)(spn + 4);
      const float* rpn = nodes + (size_t)ri1 * 32 + g * 8;
      rn0 = *(const float4*)rpn;  rn1 = *(const float4*)(rpn + 4);
      int t2 = t + 2 * GRID; if (t2 >= NPT) t2 = tn;
      const int e2 = t2 * 16 + c;
      si1 = senders[e2];  ri1 = receivers[e2];
    }

    uint pkA[5], pkB[5];
#pragma unroll
    for (int mt = 0; mt < 5; ++mt) {
      const float h0 = vrcp(1.0f + vexp2(acc[mt][0]));
      const float h1 = vrcp(1.0f + vexp2(acc[mt][1]));
      const float h2 = vrcp(1.0f + vexp2(acc[mt][2]));
      const float h3 = vrcp(1.0f + vexp2(acc[mt][3]));
      pkA[mt] = cvt_pk(h0, h1);
      pkB[mt] = cvt_pk(h2, h3);
    }
#pragma unroll
    for (int kt = 0; kt < 5; ++kt) Xr[wh][buf][kt][lane] = make_uint2(pkA[kt], pkB[kt]);
    asm volatile("s_waitcnt lgkmcnt(0)\n\ts_barrier" ::: "memory");
    uint2 q[5];
#pragma unroll
    for (int kt = 0; kt < 5; ++kt) q[kt] = Xr[wh ^ 1][buf][kt][lane];

    f32x4 oa, ob;
    if (wh == 0) {
      oa = __builtin_amdgcn_mfma_f32_16x16x32_bf16(w2f[0],
             __builtin_bit_cast(short8, make_uint4(pkA[0], pkB[0], q[0].x, q[0].y)), b2c, 0, 0, 0);
      ob = __builtin_amdgcn_mfma_f32_16x16x32_bf16(w2f[1],
             __builtin_bit_cast(short8, make_uint4(pkA[1], pkB[1], q[1].x, q[1].y)), z4, 0, 0, 0);
      oa = __builtin_amdgcn_mfma_f32_16x16x32_bf16(w2f[2],
             __builtin_bit_cast(short8, make_uint4(pkA[2], pkB[2], q[2].x, q[2].y)), oa, 0, 0, 0);
      ob = __builtin_amdgcn_mfma_f32_16x16x32_bf16(w2f[3],
             __builtin_bit_cast(short8, make_uint4(pkA[3], pkB[3], q[3].x, q[3].y)), ob, 0, 0, 0);
      oa = __builtin_amdgcn_mfma_f32_16x16x32_bf16(w2f[4],
             __builtin_bit_cast(short8, make_uint4(pkA[4], pkB[4], q[4].x, q[4].y)), oa, 0, 0, 0);
    } else {
      oa = __builtin_amdgcn_mfma_f32_16x16x32_bf16(w2f[0],
             __builtin_bit_cast(short8, make_uint4(q[0].x, q[0].y, pkA[0], pkB[0])), b2c, 0, 0, 0);
      ob = __builtin_amdgcn_mfma_f32_16x16x32_bf16(w2f[1],
             __builtin_bit_cast(short8, make_uint4(q[1].x, q[1].y, pkA[1], pkB[1])), z4, 0, 0, 0);
      oa = __builtin_amdgcn_mfma_f32_16x16x32_bf16(w2f[2],
             __builtin_bit_cast(short8, make_uint4(q[2].x, q[2].y, pkA[2], pkB[2])), oa, 0, 0, 0);
      ob = __builtin_amdgcn_mfma_f32_16x16x32_bf16(w2f[3],
             __builtin_bit_cast(short8, make_uint4(q[3].x, q[3].y, pkA[3], pkB[3])), ob, 0, 0, 0);
      oa = __builtin_amdgcn_mfma_f32_16x16x32_bf16(w2f[4],
             __builtin_bit_cast(short8, make_uint4(q[4].x, q[4].y, pkA[4], pkB[4])), oa, 0, 0, 0);
    }
    const f32x4 o = oa + ob;
    float4 st; st.x = o[0]; st.y = o[1]; st.z = o[2]; st.w = o[3];
    *(float4*)(out + (size_t)e * 32 + wh * 16 + g * 4) = st;

    t += GRID;
    e = t * 16 + c;
  }
}

extern "C" void kernel_launch(void* const* d_in, const int* in_sizes, int n_in,
                              void* d_out, int out_size, void* d_ws, size_t ws_size,
                              hipStream_t stream) {
  const float* nodes     = (const float*)d_in[0];
  const float* edges     = (const float*)d_in[1];
  const int*   senders   = (const int*)d_in[2];
  const int*   receivers = (const int*)d_in[3];
  const float* W1        = (const float*)d_in[4];
  const float* b1        = (const float*)d_in[5];
  const float* W2        = (const float*)d_in[6];
  const float* b2        = (const float*)d_in[7];
  float* out = (float*)d_out;

  if (ws_size >= (size_t)WS_BYTES) {
    ushort* ws = (ushort*)d_ws;
    prep_frags<<<80, 256, 0, stream>>>(W1, b1, W2, ws);
    prep_nodes<<<(NNODE * 4 + 255) / 256, 256, 0, stream>>>(nodes, ws + NB_OFF);
    edge_mlp_fast<<<GRID, 128, 0, stream>>>(edges, senders, receivers, b2, out, ws);
  } else {
    edge_mlp_ref<<<GRID, 128, 0, stream>>>(nodes, edges, senders, receivers,
                                           W1, b1, W2, b2, out);
  }
}

// Round 11
// 174.524 us; speedup vs baseline: 1.0195x; 1.0195x over previous
//
#include <hip/hip_runtime.h>

#define NEDGE  1600000
#define NPT    (NEDGE / 16)   // 100000 16-edge tiles
#define GRID   2000           // one wave-pair per block; <= HW co-residency
#define NIT    (NPT / GRID)   // 50 — exact, no tail
#define NNODE  100000
#define NB_OFF 32768                       // ushort offset of bf16 node cache in ws
#define WS_BYTES (65536 + NNODE * 32 * 2)  // frags + bf16 nodes = 6,465,536

typedef float f32x4  __attribute__((ext_vector_type(4)));
typedef short short8 __attribute__((ext_vector_type(8)));

static __device__ __forceinline__ ushort f2bf(float f) {
  uint u = __builtin_bit_cast(uint, f);
  return (ushort)((u + 0x7FFFu + ((u >> 16) & 1u)) >> 16);   // RNE
}
static __device__ __forceinline__ uint cvt_pk(float lo, float hi) {
  uint r; asm("v_cvt_pk_bf16_f32 %0, %1, %2" : "=v"(r) : "v"(lo), "v"(hi)); return r;
}
static __device__ __forceinline__ float vexp2(float x) {
  float r; asm("v_exp_f32 %0, %1" : "=v"(r) : "v"(x)); return r;
}
static __device__ __forceinline__ float vrcp(float x) {
  float r; asm("v_rcp_f32 %0, %1" : "=v"(r) : "v"(x)); return r;
}
static __device__ __forceinline__ short8 pack8(float4 a, float4 b) {
  uint4 u;
  u.x = cvt_pk(a.x, a.y); u.y = cvt_pk(a.z, a.w);
  u.z = cvt_pk(b.x, b.y); u.w = cvt_pk(b.z, b.w);
  return __builtin_bit_cast(short8, u);
}

// ---- ROUND-5 prep (validated): W1 (scaled -log2e, b1@k=80, zeros to 96,
// hid-permuted P) + W2 (W2^T A-frags) into MFMA fragment layout. 20480 elems.
__global__ void prep_frags(const float* __restrict__ W1, const float* __restrict__ b1,
                           const float* __restrict__ W2, ushort* __restrict__ ws) {
  const int idx = blockIdx.x * 256 + threadIdx.x;
  if (idx >= 20480) return;
  const int frag = idx >> 9;
  const int lane = (idx >> 3) & 63;
  const int j    = idx & 7;
  const int g = lane >> 4, c = lane & 15;
  ushort v;
  if (frag < 30) {                    // W1^T A-frags: frag = wh*15 + mt*3 + kt
    const int wh = frag / 15, rem = frag % 15, mt = rem / 3, kt = rem % 3;
    const int k   = kt * 32 + g * 8 + j;
    const int hid = 32 * mt + 8 * (c >> 2) + 4 * wh + (c & 3);   // permutation P
    const float s = -1.44269504088896f;
    const float val = (k < 80) ? W1[k * 160 + hid] * s
                               : (k == 80 ? b1[hid] * s : 0.0f);
    v = f2bf(val);
  } else {                            // W2^T A-frags: frag-30 = wh*5 + kt
    const int f2 = frag - 30, wh = f2 / 5, kt = f2 % 5;
    const int k = kt * 32 + g * 8 + j;
    v = f2bf(W2[k * 32 + 16 * wh + c]);
  }
  ws[idx] = v;
}

// nodes f32 -> bf16 cache (row = 32 bf16 = 64B)
__global__ void prep_nodes(const float* __restrict__ nodes, ushort* __restrict__ nb) {
  const int idx = blockIdx.x * 256 + threadIdx.x;
  if (idx >= NNODE * 4) return;
  const float4 a = ((const float4*)nodes)[idx * 2];
  const float4 b = ((const float4*)nodes)[idx * 2 + 1];
  *(short8*)(nb + (size_t)idx * 8) = pack8(a, b);
}

// R5 structure with shared-slot exchange: each wave ds_write_b64's its 8B half
// into a 16B/lane slot; after the barrier ONE ds_read_b128 yields the complete
// L2 B-fragment [wh0-half | wh1-half] — no movs, no wh branch.
__global__ __launch_bounds__(128) void edge_mlp_fast(
    const float* __restrict__ edges,
    const int* __restrict__ senders, const int* __restrict__ receivers,
    const float* __restrict__ b2, float* __restrict__ out,
    const ushort* __restrict__ ws)
{
  __shared__ uint2 X[2][5][64][2];   // [buf][kt][lane][wh] 8B halves -> 16B slots, 10 KB

  const int lane = threadIdx.x & 63;
  const int wh   = threadIdx.x >> 6;
  const int g    = lane >> 4;
  const int c    = lane & 15;
  const ushort* nb = ws + NB_OFF;

  short8 w1f[5][3];
#pragma unroll
  for (int mt = 0; mt < 5; ++mt)
#pragma unroll
    for (int kt = 0; kt < 3; ++kt)
      w1f[mt][kt] = *(const short8*)(ws + ((wh * 15 + mt * 3 + kt) * 64 + lane) * 8);
  short8 w2f[5];
#pragma unroll
  for (int kt = 0; kt < 5; ++kt)
    w2f[kt] = *(const short8*)(ws + ((30 + wh * 5 + kt) * 64 + lane) * 8);

  const float4 b2v = *(const float4*)(b2 + wh * 16 + g * 4);
  const f32x4 b2c = (f32x4){b2v.x, b2v.y, b2v.z, b2v.w};   // rides C of L2 chain a
  const f32x4 z4  = (f32x4){0.f, 0.f, 0.f, 0.f};
  const uint  cE0 = (g == 2) ? 0x3F80u : 0u;   // bf16(1.0) ones-column at k==80

  // ---- prologue: tile 0 gather + tile 1 indices (R5 pattern) ----
  int t = blockIdx.x;
  int e = t * 16 + c;
  short8 nS, nR;
  float4 ee0, ee1;
  {
    const int si = senders[e], ri = receivers[e];
    nS = *(const short8*)(nb + (size_t)si * 32 + g * 8);
    nR = *(const short8*)(nb + (size_t)ri * 32 + g * 8);
    const float* ep = edges + (size_t)e * 16 + (g & 1) * 8;
    ee0 = *(const float4*)ep;  ee1 = *(const float4*)(ep + 4);
  }
  int e1 = (t + GRID) * 16 + c;
  int si1 = senders[e1], ri1 = receivers[e1];

  for (int i = 0; i < NIT; ++i) {
    const int buf = i & 1;

    // 1) edge feats -> bf16 frag (nodes already MFMA-ready from the bf16 cache)
    uint4 ue;
    ue.x = (g < 2) ? cvt_pk(ee0.x, ee0.y) : cE0;
    ue.y = (g < 2) ? cvt_pk(ee0.z, ee0.w) : 0u;
    ue.z = (g < 2) ? cvt_pk(ee1.x, ee1.y) : 0u;
    ue.w = (g < 2) ? cvt_pk(ee1.z, ee1.w) : 0u;
    const short8 bfE = __builtin_bit_cast(short8, ue);

    // 2) L1 swapped: acc[mt] = (W1^T)(mt) x feats^T ; head C = z4
    f32x4 acc[5];
#pragma unroll
    for (int mt = 0; mt < 5; ++mt)
      acc[mt] = __builtin_amdgcn_mfma_f32_16x16x32_bf16(w1f[mt][0], nS, z4, 0, 0, 0);
#pragma unroll
    for (int mt = 0; mt < 5; ++mt)
      acc[mt] = __builtin_amdgcn_mfma_f32_16x16x32_bf16(w1f[mt][1], nR, acc[mt], 0, 0, 0);
#pragma unroll
    for (int mt = 0; mt < 5; ++mt)
      acc[mt] = __builtin_amdgcn_mfma_f32_16x16x32_bf16(w1f[mt][2], bfE, acc[mt], 0, 0, 0);

    // 3) prefetch next tile (edges, nodes, indices 2-ahead) — R5 pattern
    {
      int tn = t + GRID; if (tn >= NPT) tn = t;
      const int en = tn * 16 + c;
      const float* epn = edges + (size_t)en * 16 + (g & 1) * 8;
      ee0 = *(const float4*)epn;  ee1 = *(const float4*)(epn + 4);
      nS = *(const short8*)(nb + (size_t)si1 * 32 + g * 8);
      nR = *(const short8*)(nb + (size_t)ri1 * 32 + g * 8);
      int t2 = t + 2 * GRID; if (t2 >= NPT) t2 = tn;
      const int e2 = t2 * 16 + c;
      si1 = senders[e2];  ri1 = receivers[e2];
    }

    // 4) sigmoid in-register (scale folded): h = rcp(1+exp2(x))
    uint pkA[5], pkB[5];
#pragma unroll
    for (int mt = 0; mt < 5; ++mt) {
      const float h0 = vrcp(1.0f + vexp2(acc[mt][0]));
      const float h1 = vrcp(1.0f + vexp2(acc[mt][1]));
      const float h2 = vrcp(1.0f + vexp2(acc[mt][2]));
      const float h3 = vrcp(1.0f + vexp2(acc[mt][3]));
      pkA[mt] = cvt_pk(h0, h1);
      pkB[mt] = cvt_pk(h2, h3);
    }

    // 5) shared-slot exchange: write own 8B half into the 16B slot
#pragma unroll
    for (int kt = 0; kt < 5; ++kt)
      X[buf][kt][lane][wh] = make_uint2(pkA[kt], pkB[kt]);
    asm volatile("s_waitcnt lgkmcnt(0)\n\ts_barrier" ::: "memory");

    // 6) L2: ONE b128 read per kt = complete B-frag; dual MFMA chains
    f32x4 oa, ob;
    {
      const short8 bb0 = *(const short8*)&X[buf][0][lane][0];
      const short8 bb1 = *(const short8*)&X[buf][1][lane][0];
      const short8 bb2 = *(const short8*)&X[buf][2][lane][0];
      const short8 bb3 = *(const short8*)&X[buf][3][lane][0];
      const short8 bb4 = *(const short8*)&X[buf][4][lane][0];
      oa = __builtin_amdgcn_mfma_f32_16x16x32_bf16(w2f[0], bb0, b2c, 0, 0, 0);
      ob = __builtin_amdgcn_mfma_f32_16x16x32_bf16(w2f[1], bb1, z4, 0, 0, 0);
      oa = __builtin_amdgcn_mfma_f32_16x16x32_bf16(w2f[2], bb2, oa, 0, 0, 0);
      ob = __builtin_amdgcn_mfma_f32_16x16x32_bf16(w2f[3], bb3, ob, 0, 0, 0);
      oa = __builtin_amdgcn_mfma_f32_16x16x32_bf16(w2f[4], bb4, oa, 0, 0, 0);
    }
    const f32x4 o = oa + ob;

    // 7) coalesced store
    float4 st; st.x = o[0]; st.y = o[1]; st.z = o[2]; st.w = o[3];
    *(float4*)(out + (size_t)e * 32 + wh * 16 + g * 4) = st;

    t += GRID;
    e = t * 16 + c;
  }
}

// Fallback (ws too small): round-5 depth-1 path, frags built in-kernel.
__global__ __launch_bounds__(128) void edge_mlp_ref(
    const float* __restrict__ nodes, const float* __restrict__ edges,
    const int* __restrict__ senders, const int* __restrict__ receivers,
    const float* __restrict__ W1, const float* __restrict__ b1,
    const float* __restrict__ W2, const float* __restrict__ b2,
    float* __restrict__ out)
{
  __shared__ uint2 Xr[2][2][5][64];
  const int lane = threadIdx.x & 63;
  const int wh   = threadIdx.x >> 6;
  const int g    = lane >> 4;
  const int c    = lane & 15;

  short8 w1f[5][3];
  short8 w2f[5];
  const float s = -1.44269504088896f;
  const int hidb = 8 * (c >> 2) + 4 * wh + (c & 3);
#pragma unroll
  for (int mt = 0; mt < 5; ++mt)
#pragma unroll
    for (int kt = 0; kt < 3; ++kt) {
      const int hid = 32 * mt + hidb;
      uint d[4];
#pragma unroll
      for (int dw = 0; dw < 4; ++dw) {
        const int k0 = kt * 32 + g * 8 + dw * 2, k1 = k0 + 1;
        const float f0 = (k0 < 80) ? W1[k0 * 160 + hid] * s : (k0 == 80 ? b1[hid] * s : 0.f);
        const float f1 = (k1 < 80) ? W1[k1 * 160 + hid] * s : (k1 == 80 ? b1[hid] * s : 0.f);
        d[dw] = (uint)f2bf(f0) | ((uint)f2bf(f1) << 16);
      }
      w1f[mt][kt] = __builtin_bit_cast(short8, make_uint4(d[0], d[1], d[2], d[3]));
    }
#pragma unroll
  for (int kt = 0; kt < 5; ++kt) {
    uint d[4];
#pragma unroll
    for (int dw = 0; dw < 4; ++dw) {
      const int k = kt * 32 + g * 8 + dw * 2;
      d[dw] = (uint)f2bf(W2[k * 32 + wh * 16 + c]) |
              ((uint)f2bf(W2[(k + 1) * 32 + wh * 16 + c]) << 16);
    }
    w2f[kt] = __builtin_bit_cast(short8, make_uint4(d[0], d[1], d[2], d[3]));
  }
  const float4 b2v = *(const float4*)(b2 + wh * 16 + g * 4);
  const f32x4 b2c = (f32x4){b2v.x, b2v.y, b2v.z, b2v.w};
  const f32x4 z4  = (f32x4){0.f, 0.f, 0.f, 0.f};
  const uint  cE0 = (g == 2) ? 0x3F80u : 0u;

  int t = blockIdx.x;
  int e = t * 16 + c;
  float4 sn0, sn1, rn0, rn1, ee0, ee1;
  {
    const int si = senders[e], ri = receivers[e];
    const float* sp = nodes + (size_t)si * 32 + g * 8;
    sn0 = *(const float4*)sp;  sn1 = *(const float4*)(sp + 4);
    const float* rp = nodes + (size_t)ri * 32 + g * 8;
    rn0 = *(const float4*)rp;  rn1 = *(const float4*)(rp + 4);
    const float* ep = edges + (size_t)e * 16 + (g & 1) * 8;
    ee0 = *(const float4*)ep;  ee1 = *(const float4*)(ep + 4);
  }
  int e1 = (t + GRID) * 16 + c;
  int si1 = senders[e1], ri1 = receivers[e1];

  for (int i = 0; i < NIT; ++i) {
    const int buf = i & 1;
    uint4 ue;
    ue.x = (g < 2) ? cvt_pk(ee0.x, ee0.y) : cE0;
    ue.y = (g < 2) ? cvt_pk(ee0.z, ee0.w) : 0u;
    ue.z = (g < 2) ? cvt_pk(ee1.x, ee1.y) : 0u;
    ue.w = (g < 2) ? cvt_pk(ee1.z, ee1.w) : 0u;
    const short8 bfE = __builtin_bit_cast(short8, ue);
    const short8 bfS = pack8(sn0, sn1);
    const short8 bfR = pack8(rn0, rn1);

    f32x4 acc[5];
#pragma unroll
    for (int mt = 0; mt < 5; ++mt)
      acc[mt] = __builtin_amdgcn_mfma_f32_16x16x32_bf16(w1f[mt][0], bfS, z4, 0, 0, 0);
#pragma unroll
    for (int mt = 0; mt < 5; ++mt)
      acc[mt] = __builtin_amdgcn_mfma_f32_16x16x32_bf16(w1f[mt][1], bfR, acc[mt], 0, 0, 0);
#pragma unroll
    for (int mt = 0; mt < 5; ++mt)
      acc[mt] = __builtin_amdgcn_mfma_f32_16x16x32_bf16(w1f[mt][2], bfE, acc[mt], 0, 0, 0);

    {
      int tn = t + GRID; if (tn >= NPT) tn = t;
      const int en = tn * 16 + c;
      const float* epn = edges + (size_t)en * 16 + (g & 1) * 8;
      ee0 = *(const float4*)epn;  ee1 = *(const float4*)(epn + 4);
      const float* spn = nodes + (size_t)si1 * 32 + g * 8;
      sn0 = *(const float4*)spn;  sn1 = *(const float4*)(spn + 4);
      const float* rpn = nodes + (size_t)ri1 * 32 + g * 8;
      rn0 = *(const float4*)rpn;  rn1 = *(const float4*)(rpn + 4);
      int t2 = t + 2 * GRID; if (t2 >= NPT) t2 = tn;
      const int e2 = t2 * 16 + c;
      si1 = senders[e2];  ri1 = receivers[e2];
    }

    uint pkA[5], pkB[5];
#pragma unroll
    for (int mt = 0; mt < 5; ++mt) {
      const float h0 = vrcp(1.0f + vexp2(acc[mt][0]));
      const float h1 = vrcp(1.0f + vexp2(acc[mt][1]));
      const float h2 = vrcp(1.0f + vexp2(acc[mt][2]));
      const float h3 = vrcp(1.0f + vexp2(acc[mt][3]));
      pkA[mt] = cvt_pk(h0, h1);
      pkB[mt] = cvt_pk(h2, h3);
    }
#pragma unroll
    for (int kt = 0; kt < 5; ++kt) Xr[wh][buf][kt][lane] = make_uint2(pkA[kt], pkB[kt]);
    asm volatile("s_waitcnt lgkmcnt(0)\n\ts_barrier" ::: "memory");
    uint2 q[5];
#pragma unroll
    for (int kt = 0; kt < 5; ++kt) q[kt] = Xr[wh ^ 1][buf][kt][lane];

    f32x4 oa, ob;
    if (wh == 0) {
      oa = __builtin_amdgcn_mfma_f32_16x16x32_bf16(w2f[0],
             __builtin_bit_cast(short8, make_uint4(pkA[0], pkB[0], q[0].x, q[0].y)), b2c, 0, 0, 0);
      ob = __builtin_amdgcn_mfma_f32_16x16x32_bf16(w2f[1],
             __builtin_bit_cast(short8, make_uint4(pkA[1], pkB[1], q[1].x, q[1].y)), z4, 0, 0, 0);
      oa = __builtin_amdgcn_mfma_f32_16x16x32_bf16(w2f[2],
             __builtin_bit_cast(short8, make_uint4(pkA[2], pkB[2], q[2].x, q[2].y)), oa, 0, 0, 0);
      ob = __builtin_amdgcn_mfma_f32_16x16x32_bf16(w2f[3],
             __builtin_bit_cast(short8, make_uint4(pkA[3], pkB[3], q[3].x, q[3].y)), ob, 0, 0, 0);
      oa = __builtin_amdgcn_mfma_f32_16x16x32_bf16(w2f[4],
             __builtin_bit_cast(short8, make_uint4(pkA[4], pkB[4], q[4].x, q[4].y)), oa, 0, 0, 0);
    } else {
      oa = __builtin_amdgcn_mfma_f32_16x16x32_bf16(w2f[0],
             __builtin_bit_cast(short8, make_uint4(q[0].x, q[0].y, pkA[0], pkB[0])), b2c, 0, 0, 0);
      ob = __builtin_amdgcn_mfma_f32_16x16x32_bf16(w2f[1],
             __builtin_bit_cast(short8, make_uint4(q[1].x, q[1].y, pkA[1], pkB[1])), z4, 0, 0, 0);
      oa = __builtin_amdgcn_mfma_f32_16x16x32_bf16(w2f[2],
             __builtin_bit_cast(short8, make_uint4(q[2].x, q[2].y, pkA[2], pkB[2])), oa, 0, 0, 0);
      ob = __builtin_amdgcn_mfma_f32_16x16x32_bf16(w2f[3],
             __builtin_bit_cast(short8, make_uint4(q[3].x, q[3].y, pkA[3], pkB[3])), ob, 0, 0, 0);
      oa = __builtin_amdgcn_mfma_f32_16x16x32_bf16(w2f[4],
             __builtin_bit_cast(short8, make_uint4(q[4].x, q[4].y, pkA[4], pkB[4])), oa, 0, 0, 0);
    }
    const f32x4 o = oa + ob;
    float4 st; st.x = o[0]; st.y = o[1]; st.z = o[2]; st.w = o[3];
    *(float4*)(out + (size_t)e * 32 + wh * 16 + g * 4) = st;

    t += GRID;
    e = t * 16 + c;
  }
}

extern "C" void kernel_launch(void* const* d_in, const int* in_sizes, int n_in,
                              void* d_out, int out_size, void* d_ws, size_t ws_size,
                              hipStream_t stream) {
  const float* nodes     = (const float*)d_in[0];
  const float* edges     = (const float*)d_in[1];
  const int*   senders   = (const int*)d_in[2];
  const int*   receivers = (const int*)d_in[3];
  const float* W1        = (const float*)d_in[4];
  const float* b1        = (const float*)d_in[5];
  const float* W2        = (const float*)d_in[6];
  const float* b2        = (const float*)d_in[7];
  float* out = (float*)d_out;

  if (ws_size >= (size_t)WS_BYTES) {
    ushort* ws = (ushort*)d_ws;
    prep_frags<<<80, 256, 0, stream>>>(W1, b1, W2, ws);
    prep_nodes<<<(NNODE * 4 + 255) / 256, 256, 0, stream>>>(nodes, ws + NB_OFF);
    edge_mlp_fast<<<GRID, 128, 0, stream>>>(edges, senders, receivers, b2, out, ws);
  } else {
    edge_mlp_ref<<<GRID, 128, 0, stream>>>(nodes, edges, senders, receivers,
                                           W1, b1, W2, b2, out);
  }
}

// Round 13
// 158.264 us; speedup vs baseline: 1.1243x; 1.1027x over previous
//
#include <hip/hip_runtime.h>

#define NEDGE  1600000
#define NPT    (NEDGE / 16)   // 100000 16-edge tiles
#define GRID   2500           // one wave-pair per block
#define NIT    (NPT / GRID)   // 40 — exact, no tail
#define NNODE  100000
#define NB_OFF 32768                       // ushort offset of bf16 node cache in ws
#define WS_BYTES (65536 + NNODE * 32 * 2)  // frags + bf16 nodes = 6,465,536

typedef float f32x4  __attribute__((ext_vector_type(4)));
typedef short short8 __attribute__((ext_vector_type(8)));

static __device__ __forceinline__ ushort f2bf(float f) {
  uint u = __builtin_bit_cast(uint, f);
  return (ushort)((u + 0x7FFFu + ((u >> 16) & 1u)) >> 16);   // RNE
}
static __device__ __forceinline__ uint cvt_pk(float lo, float hi) {
  uint r; asm("v_cvt_pk_bf16_f32 %0, %1, %2" : "=v"(r) : "v"(lo), "v"(hi)); return r;
}
static __device__ __forceinline__ float vexp2(float x) {
  float r; asm("v_exp_f32 %0, %1" : "=v"(r) : "v"(x)); return r;
}
static __device__ __forceinline__ float vrcp(float x) {
  float r; asm("v_rcp_f32 %0, %1" : "=v"(r) : "v"(x)); return r;
}
static __device__ __forceinline__ short8 pack8(float4 a, float4 b) {
  uint4 u;
  u.x = cvt_pk(a.x, a.y); u.y = cvt_pk(a.z, a.w);
  u.z = cvt_pk(b.x, b.y); u.w = cvt_pk(b.z, b.w);
  return __builtin_bit_cast(short8, u);
}

// ---- ROUND-5 prep (validated): W1 (scaled -log2e, b1@k=80, zeros to 96,
// hid-permuted P) + W2 (W2^T A-frags) into MFMA fragment layout. 20480 elems.
__global__ void prep_frags(const float* __restrict__ W1, const float* __restrict__ b1,
                           const float* __restrict__ W2, ushort* __restrict__ ws) {
  const int idx = blockIdx.x * 256 + threadIdx.x;
  if (idx >= 20480) return;
  const int frag = idx >> 9;
  const int lane = (idx >> 3) & 63;
  const int j    = idx & 7;
  const int g = lane >> 4, c = lane & 15;
  ushort v;
  if (frag < 30) {                    // W1^T A-frags: frag = wh*15 + mt*3 + kt
    const int wh = frag / 15, rem = frag % 15, mt = rem / 3, kt = rem % 3;
    const int k   = kt * 32 + g * 8 + j;
    const int hid = 32 * mt + 8 * (c >> 2) + 4 * wh + (c & 3);   // permutation P
    const float s = -1.44269504088896f;
    const float val = (k < 80) ? W1[k * 160 + hid] * s
                               : (k == 80 ? b1[hid] * s : 0.0f);
    v = f2bf(val);
  } else {                            // W2^T A-frags: frag-30 = wh*5 + kt
    const int f2 = frag - 30, wh = f2 / 5, kt = f2 % 5;
    const int k = kt * 32 + g * 8 + j;
    v = f2bf(W2[k * 32 + 16 * wh + c]);
  }
  ws[idx] = v;
}

// nodes f32 -> bf16 cache (row = 32 bf16 = 64B)
__global__ void prep_nodes(const float* __restrict__ nodes, ushort* __restrict__ nb) {
  const int idx = blockIdx.x * 256 + threadIdx.x;
  if (idx >= NNODE * 4) return;
  const float4 a = ((const float4*)nodes)[idx * 2];
  const float4 b = ((const float4*)nodes)[idx * 2 + 1];
  *(short8*)(nb + (size_t)idx * 8) = pack8(a, b);
}

template <bool USE_WS>
__global__ __launch_bounds__(128) void edge_mlp(
    const float* __restrict__ nodes, const float* __restrict__ edges,
    const int* __restrict__ senders, const int* __restrict__ receivers,
    const float* __restrict__ W1, const float* __restrict__ b1,
    const float* __restrict__ W2, const float* __restrict__ b2,
    float* __restrict__ out, const ushort* __restrict__ ws)
{
  __shared__ uint2 X[2][2][5][64];   // [wave][dbuf][kt][lane] h-half exchange, 10 KB

  const int lane = threadIdx.x & 63;
  const int wh   = threadIdx.x >> 6;
  const int g    = lane >> 4;
  const int c    = lane & 15;
  const ushort* nb = USE_WS ? (ws + NB_OFF) : nullptr;

  // ---- weight fragments in registers ----
  short8 w1f[5][3];
  short8 w2f[5];
  if constexpr (USE_WS) {
#pragma unroll
    for (int mt = 0; mt < 5; ++mt)
#pragma unroll
      for (int kt = 0; kt < 3; ++kt)
        w1f[mt][kt] = *(const short8*)(ws + ((wh * 15 + mt * 3 + kt) * 64 + lane) * 8);
#pragma unroll
    for (int kt = 0; kt < 5; ++kt)
      w2f[kt] = *(const short8*)(ws + ((30 + wh * 5 + kt) * 64 + lane) * 8);
  } else {
    const float s = -1.44269504088896f;
    const int hidb = 8 * (c >> 2) + 4 * wh + (c & 3);
#pragma unroll
    for (int mt = 0; mt < 5; ++mt)
#pragma unroll
      for (int kt = 0; kt < 3; ++kt) {
        const int hid = 32 * mt + hidb;
        uint d[4];
#pragma unroll
        for (int dw = 0; dw < 4; ++dw) {
          const int k0 = kt * 32 + g * 8 + dw * 2, k1 = k0 + 1;
          const float f0 = (k0 < 80) ? W1[k0 * 160 + hid] * s : (k0 == 80 ? b1[hid] * s : 0.f);
          const float f1 = (k1 < 80) ? W1[k1 * 160 + hid] * s : (k1 == 80 ? b1[hid] * s : 0.f);
          d[dw] = (uint)f2bf(f0) | ((uint)f2bf(f1) << 16);
        }
        w1f[mt][kt] = __builtin_bit_cast(short8, make_uint4(d[0], d[1], d[2], d[3]));
      }
#pragma unroll
    for (int kt = 0; kt < 5; ++kt) {
      uint d[4];
#pragma unroll
      for (int dw = 0; dw < 4; ++dw) {
        const int k = kt * 32 + g * 8 + dw * 2;
        d[dw] = (uint)f2bf(W2[k * 32 + wh * 16 + c]) |
                ((uint)f2bf(W2[(k + 1) * 32 + wh * 16 + c]) << 16);
      }
      w2f[kt] = __builtin_bit_cast(short8, make_uint4(d[0], d[1], d[2], d[3]));
    }
  }
  const float4 b2v = *(const float4*)(b2 + wh * 16 + g * 4);
  const f32x4 b2c = (f32x4){b2v.x, b2v.y, b2v.z, b2v.w};
  const f32x4 z4  = (f32x4){0.f, 0.f, 0.f, 0.f};
  const uint  cE0 = (g == 2) ? 0x3F80u : 0u;   // bf16(1.0) at k==80

  // ---- prologue: tile 0 gather + tile 1 indices ----
  int t = blockIdx.x;
  int e = t * 16 + c;
  short8 bfS_p, bfR_p;                 // USE_WS path: direct bf16 node frags
  float4 sn0, sn1, rn0, rn1;           // fallback path: f32 node rows
  float4 ee0, ee1;
  {
    const int si = senders[e], ri = receivers[e];
    if constexpr (USE_WS) {
      bfS_p = *(const short8*)(nb + (size_t)si * 32 + g * 8);
      bfR_p = *(const short8*)(nb + (size_t)ri * 32 + g * 8);
    } else {
      const float* sp = nodes + (size_t)si * 32 + g * 8;
      sn0 = *(const float4*)sp;  sn1 = *(const float4*)(sp + 4);
      const float* rp = nodes + (size_t)ri * 32 + g * 8;
      rn0 = *(const float4*)rp;  rn1 = *(const float4*)(rp + 4);
    }
    const float* ep = edges + (size_t)e * 16 + (g & 1) * 8;
    ee0 = *(const float4*)ep;  ee1 = *(const float4*)(ep + 4);
  }
  int e1 = (t + GRID) * 16 + c;
  int si1 = senders[e1], ri1 = receivers[e1];

  for (int i = 0; i < NIT; ++i) {
    const int buf = i & 1;

    // 1) edge feats -> bf16 frag (nodes need no pack on the USE_WS path)
    uint4 ue;
    ue.x = (g < 2) ? cvt_pk(ee0.x, ee0.y) : cE0;
    ue.y = (g < 2) ? cvt_pk(ee0.z, ee0.w) : 0u;
    ue.z = (g < 2) ? cvt_pk(ee1.x, ee1.y) : 0u;
    ue.w = (g < 2) ? cvt_pk(ee1.z, ee1.w) : 0u;
    const short8 bfE = __builtin_bit_cast(short8, ue);
    short8 bfS, bfR;
    if constexpr (USE_WS) { bfS = bfS_p;            bfR = bfR_p; }
    else                  { bfS = pack8(sn0, sn1);  bfR = pack8(rn0, rn1); }

    // 2) L1 swapped: acc[mt] = (W1^T)(mt) x feats^T   [T5: boost MFMA cluster]
    f32x4 acc[5];
    __builtin_amdgcn_s_setprio(1);
#pragma unroll
    for (int mt = 0; mt < 5; ++mt)
      acc[mt] = __builtin_amdgcn_mfma_f32_16x16x32_bf16(w1f[mt][0], bfS, z4, 0, 0, 0);
#pragma unroll
    for (int mt = 0; mt < 5; ++mt)
      acc[mt] = __builtin_amdgcn_mfma_f32_16x16x32_bf16(w1f[mt][1], bfR, acc[mt], 0, 0, 0);
#pragma unroll
    for (int mt = 0; mt < 5; ++mt)
      acc[mt] = __builtin_amdgcn_mfma_f32_16x16x32_bf16(w1f[mt][2], bfE, acc[mt], 0, 0, 0);
    __builtin_amdgcn_s_setprio(0);

    // 3) prefetch next tile (edges, nodes, then indices 2-ahead)
    {
      int tn = t + GRID; if (tn >= NPT) tn = t;
      const int en = tn * 16 + c;
      const float* epn = edges + (size_t)en * 16 + (g & 1) * 8;
      ee0 = *(const float4*)epn;  ee1 = *(const float4*)(epn + 4);
      if constexpr (USE_WS) {
        bfS_p = *(const short8*)(nb + (size_t)si1 * 32 + g * 8);
        bfR_p = *(const short8*)(nb + (size_t)ri1 * 32 + g * 8);
      } else {
        const float* spn = nodes + (size_t)si1 * 32 + g * 8;
        sn0 = *(const float4*)spn;  sn1 = *(const float4*)(spn + 4);
        const float* rpn = nodes + (size_t)ri1 * 32 + g * 8;
        rn0 = *(const float4*)rpn;  rn1 = *(const float4*)(rpn + 4);
      }
      int t2 = t + 2 * GRID; if (t2 >= NPT) t2 = tn;
      const int e2 = t2 * 16 + c;
      si1 = senders[e2];  ri1 = receivers[e2];
    }

    // 4) sigmoid in-register (scale folded into W1/b1): h = rcp(1+exp2(x))
    uint pkA[5], pkB[5];
#pragma unroll
    for (int mt = 0; mt < 5; ++mt) {
      const float h0 = vrcp(1.0f + vexp2(acc[mt][0]));
      const float h1 = vrcp(1.0f + vexp2(acc[mt][1]));
      const float h2 = vrcp(1.0f + vexp2(acc[mt][2]));
      const float h3 = vrcp(1.0f + vexp2(acc[mt][3]));
      pkA[mt] = cvt_pk(h0, h1);
      pkB[mt] = cvt_pk(h2, h3);
    }

    // 5) lane-aligned half exchange with partner wave
#pragma unroll
    for (int kt = 0; kt < 5; ++kt) X[wh][buf][kt][lane] = make_uint2(pkA[kt], pkB[kt]);
    asm volatile("s_waitcnt lgkmcnt(0)\n\ts_barrier" ::: "memory");
    uint2 q[5];
#pragma unroll
    for (int kt = 0; kt < 5; ++kt) q[kt] = X[wh ^ 1][buf][kt][lane];

    // 6) L2 swapped: o = (W2^T rows) x h^T ; B-frag = [own pk | partner pk]
    f32x4 oa = (f32x4){b2c[0], b2c[1], b2c[2], b2c[3]};
    f32x4 ob = (f32x4){0.f, 0.f, 0.f, 0.f};
    __builtin_amdgcn_s_setprio(1);
    if (wh == 0) {
#pragma unroll
      for (int kt = 0; kt < 5; ++kt) {
        const short8 bb = __builtin_bit_cast(short8,
            make_uint4(pkA[kt], pkB[kt], q[kt].x, q[kt].y));
        if (kt & 1) ob = __builtin_amdgcn_mfma_f32_16x16x32_bf16(w2f[kt], bb, ob, 0, 0, 0);
        else        oa = __builtin_amdgcn_mfma_f32_16x16x32_bf16(w2f[kt], bb, oa, 0, 0, 0);
      }
    } else {
#pragma unroll
      for (int kt = 0; kt < 5; ++kt) {
        const short8 bb = __builtin_bit_cast(short8,
            make_uint4(q[kt].x, q[kt].y, pkA[kt], pkB[kt]));
        if (kt & 1) ob = __builtin_amdgcn_mfma_f32_16x16x32_bf16(w2f[kt], bb, ob, 0, 0, 0);
        else        oa = __builtin_amdgcn_mfma_f32_16x16x32_bf16(w2f[kt], bb, oa, 0, 0, 0);
      }
    }
    __builtin_amdgcn_s_setprio(0);
    const f32x4 o = oa + ob;

    // 7) coalesced store
    float4 st; st.x = o[0]; st.y = o[1]; st.z = o[2]; st.w = o[3];
    *(float4*)(out + (size_t)e * 32 + wh * 16 + g * 4) = st;

    t += GRID;
    e = t * 16 + c;
  }
}

extern "C" void kernel_launch(void* const* d_in, const int* in_sizes, int n_in,
                              void* d_out, int out_size, void* d_ws, size_t ws_size,
                              hipStream_t stream) {
  const float* nodes     = (const float*)d_in[0];
  const float* edges     = (const float*)d_in[1];
  const int*   senders   = (const int*)d_in[2];
  const int*   receivers = (const int*)d_in[3];
  const float* W1        = (const float*)d_in[4];
  const float* b1        = (const float*)d_in[5];
  const float* W2        = (const float*)d_in[6];
  const float* b2        = (const float*)d_in[7];
  float* out = (float*)d_out;

  if (ws_size >= (size_t)WS_BYTES) {
    ushort* ws = (ushort*)d_ws;
    prep_frags<<<80, 256, 0, stream>>>(W1, b1, W2, ws);
    prep_nodes<<<(NNODE * 4 + 255) / 256, 256, 0, stream>>>(nodes, ws + NB_OFF);
    edge_mlp<true><<<GRID, 128, 0, stream>>>(nodes, edges, senders, receivers,
                                             W1, b1, W2, b2, out, ws);
  } else {
    edge_mlp<false><<<GRID, 128, 0, stream>>>(nodes, edges, senders, receivers,
                                              W1, b1, W2, b2, out, nullptr);
  }
}